// Round 6
// baseline (358.476 us; speedup 1.0000x reference)
//
#include <hip/hip_runtime.h>
#include <cstdint>

#define DEV __device__ __forceinline__

typedef __attribute__((ext_vector_type(8))) short bf16x8;
typedef __attribute__((ext_vector_type(4))) float f32x4;

DEV unsigned short f2bf(float x){
  union { float f; unsigned u; } c; c.f = x;
  unsigned r = c.u + 0x7fffu + ((c.u >> 16) & 1u);
  return (unsigned short)(r >> 16);
}
DEV float bf2f(unsigned short h){
  union { unsigned u; float f; } c; c.u = ((unsigned)h) << 16;
  return c.f;
}
DEV float gelu_f(float x){ return 0.5f * x * (1.f + erff(x * 0.70710678118654752440f)); }

DEV f32x4 mfma16(bf16x8 a, bf16x8 b, f32x4 c){
  return __builtin_amdgcn_mfma_f32_16x16x32_bf16(a, b, c, 0, 0, 0);
}

// block_sum: 256 threads (4 waves)
DEV float block_sum(float v, float* red, int tid){
  #pragma unroll
  for (int o = 32; o > 0; o >>= 1) v += __shfl_down(v, o);
  if ((tid & 63) == 0) red[tid >> 6] = v;
  __syncthreads();
  float s = red[0] + red[1] + red[2] + red[3];
  __syncthreads();
  return s;
}

// ---------------- constants ----------------
// B=16 N=64 D=256 CI=256 H=W=64 P=36 HEADS=8 HD=32 HID=1024 TOTAL=66832 T=1024
// cm fragment order: n = c*256+d (c = in-dim, d = out-dim) lives at
//   f(n) = (c>>5)*8192 + (d>>6)*2048 + ((d>>4)&3)*512 + ((c>>3)&3)*128 + (d&15)*8 + (c&7)
// params3[t*65536 + f] for t<1024 (134MB). sm tail keeps blocked layout:
//   params3[(n>>6)*65536 + t*64 + (n&63)] for n in [65536, 66880).
// Consumer B-frag (wave,j,cc): 64 lanes x 16B = 1KB contiguous at
//   t*65536 + cc*8192 + wave*2048 + j*512 + lane*8.

// ---------------- kernel 1: per-token prep ----------------
__global__ __launch_bounds__(256) void k_prep(
    const float* __restrict__ embed, const float* __restrict__ roi,
    const float* __restrict__ g_adj, const float* __restrict__ b_adj, const float* __restrict__ w_adj,
    const float* __restrict__ g_off, const float* __restrict__ b_off, const float* __restrict__ w_off,
    const float* __restrict__ off_bias,
    const float* __restrict__ g_pg, const float* __restrict__ b_pg,
    const float* __restrict__ w_pg1, const float* __restrict__ b_pg1,
    float* __restrict__ pts, float* __restrict__ hbuf)
{
  __shared__ float red[4];
  __shared__ float xln[256];
  __shared__ float offs[72];
  __shared__ float lg[4];
  __shared__ float stat[8];
  const int t = blockIdx.x, tid = threadIdx.x;
  float e = embed[t * 256 + tid];
  float mean = block_sum(e, red, tid) * (1.f / 256.f);
  float dv = e - mean;
  float var = block_sum(dv * dv, red, tid) * (1.f / 256.f);
  xln[tid] = dv * rsqrtf(var + 1e-5f);
  __syncthreads();
  if (tid < 4){
    float a0 = 0.f, a1 = 0.f, a2 = 0.f, a3 = 0.f;
    #pragma unroll 4
    for (int c = 0; c < 256; c += 4){
      a0 += (xln[c+0] * g_adj[c+0] + b_adj[c+0]) * w_adj[(c+0) * 4 + tid];
      a1 += (xln[c+1] * g_adj[c+1] + b_adj[c+1]) * w_adj[(c+1) * 4 + tid];
      a2 += (xln[c+2] * g_adj[c+2] + b_adj[c+2]) * w_adj[(c+2) * 4 + tid];
      a3 += (xln[c+3] * g_adj[c+3] + b_adj[c+3]) * w_adj[(c+3) * 4 + tid];
    }
    lg[tid] = (a0 + a1) + (a2 + a3);
  } else if (tid < 76){
    int j = tid - 4;
    float a0 = 0.f, a1 = 0.f, a2 = 0.f, a3 = 0.f;
    #pragma unroll 4
    for (int c = 0; c < 256; c += 4){
      a0 += (xln[c+0] * g_off[c+0] + b_off[c+0]) * w_off[(c+0) * 72 + j];
      a1 += (xln[c+1] * g_off[c+1] + b_off[c+1]) * w_off[(c+1) * 72 + j];
      a2 += (xln[c+2] * g_off[c+2] + b_off[c+2]) * w_off[(c+2) * 72 + j];
      a3 += (xln[c+3] * g_off[c+3] + b_off[c+3]) * w_off[(c+3) * 72 + j];
    }
    offs[j] = (a0 + a1) + (a2 + a3) + off_bias[j];
  } else if (tid < 140){
    int j = tid - 76;
    float a0 = 0.f, a1 = 0.f, a2 = 0.f, a3 = 0.f;
    #pragma unroll 4
    for (int c = 0; c < 256; c += 4){
      a0 += (xln[c+0] * g_pg[c+0] + b_pg[c+0]) * w_pg1[(c+0) * 64 + j];
      a1 += (xln[c+1] * g_pg[c+1] + b_pg[c+1]) * w_pg1[(c+1) * 64 + j];
      a2 += (xln[c+2] * g_pg[c+2] + b_pg[c+2]) * w_pg1[(c+2) * 64 + j];
      a3 += (xln[c+3] * g_pg[c+3] + b_pg[c+3]) * w_pg1[(c+3) * 64 + j];
    }
    hbuf[t * 64 + j] = (a0 + a1) + (a2 + a3) + b_pg1[j];
  }
  __syncthreads();
  if (tid == 0){
    float x0 = roi[t*4+0], y0 = roi[t*4+1], x1 = roi[t*4+2], y1 = roi[t*4+3];
    float cx = (x0 + x1) * 0.5f, cy = (y0 + y1) * 0.5f;
    float w = fabsf(x1 - x0), hh = fabsf(y1 - y0);
    cx += lg[0] * w; cy += lg[1] * hh;
    w *= expf(lg[2]); hh *= expf(lg[3]);
    stat[0] = cx; stat[1] = cy; stat[2] = w; stat[3] = hh;
  }
  if (tid < 2){
    float mu = 0.f;
    for (int p = 0; p < 36; ++p) mu += offs[p*2 + tid];
    mu *= (1.f / 36.f);
    float v2 = 0.f;
    for (int p = 0; p < 36; ++p){ float d = offs[p*2 + tid] - mu; v2 += d * d; }
    float sd = sqrtf(v2 * (1.f / 35.f)) + 1e-7f;   // ddof=1
    stat[4 + tid] = mu; stat[6 + tid] = 1.f / (3.f * sd);
  }
  __syncthreads();
  if (tid < 72){
    int c = tid & 1;
    pts[t * 72 + tid] = stat[c] + (offs[tid] - stat[4 + c]) * stat[6 + c] * stat[2 + c];
  }
}

// ---------------- kernel 1b: w2 -> fragment-ordered transposed w2f [66880][64] + b2f
// w2f[f(n)][k] = w2[k][n]; b2f[f(n)] = b2[n]; zero-padded past 66832.
__global__ __launch_bounds__(256) void k_w2t(const float* __restrict__ w2,
                                             const float* __restrict__ b2,
                                             float* __restrict__ w2f,
                                             float* __restrict__ b2f)
{
  __shared__ float tile[64][65];
  const int nc = blockIdx.x, tid = threadIdx.x;
  const int n0 = nc * 64;
  {
    int k = tid >> 2, i0 = (tid & 3) * 16;
    #pragma unroll
    for (int i = 0; i < 16; ++i){
      int n = n0 + i0 + i;
      tile[k][i0 + i] = (n < 66832) ? w2[(size_t)k * 66832 + n] : 0.f;
    }
  }
  __syncthreads();
  {
    int nl = tid >> 2, k0 = (tid & 3) * 16;
    int n = n0 + nl;
    int np;
    if (n < 65536){
      int c = n >> 8, d = n & 255;
      np = (c >> 5) * 8192 + (d >> 6) * 2048 + ((d >> 4) & 3) * 512
         + ((c >> 3) & 3) * 128 + (d & 15) * 8 + (c & 7);
    } else np = n;
    float* dst = w2f + (size_t)np * 64 + k0;
    #pragma unroll
    for (int i = 0; i < 16; ++i) dst[i] = tile[k0 + i][nl];
    if ((tid & 3) == 0) b2f[np] = (n < 66832) ? b2[n] : 0.f;
  }
}

// ---------------- kernel 2: img [B,C,H,W] f32 -> [B,H,W,C] bf16 ----------------
__global__ __launch_bounds__(256) void k_transpose(const float* __restrict__ img,
                                                   unsigned short* __restrict__ imgT)
{
  __shared__ float tile[128][65];
  const int blk = blockIdx.x, tid = threadIdx.x;
  const int b = blk >> 6, y = blk & 63;
  for (int half = 0; half < 2; ++half){
    int c_loc = tid >> 1, x0 = (tid & 1) * 32;
    const float* src = img + (((size_t)(b * 256 + half * 128 + c_loc)) * 64 + y) * 64 + x0;
    #pragma unroll
    for (int i = 0; i < 32; ++i) tile[c_loc][x0 + i] = src[i];
    __syncthreads();
    int c = tid & 127, xh = tid >> 7;
    size_t obase = ((size_t)(b * 64 + y)) * 64 * 256 + half * 128 + c;
    for (int xx = 0; xx < 64; xx += 2){
      int x = xx + xh;
      imgT[obase + (size_t)x * 256] = f2bf(tile[c][x]);
    }
    __syncthreads();
  }
}

// ---------------- kernel 3: bilinear sample -> sampled48 [T,48,256] bf16 (rows 36+ zero)
__global__ __launch_bounds__(256) void k_sample(const unsigned short* __restrict__ imgT,
                                                const float* __restrict__ pts,
                                                unsigned short* __restrict__ sampled48)
{
  __shared__ float lpts[72];
  const int t = blockIdx.x, tid = threadIdx.x;
  const int b = t >> 6;
  if (tid < 72) lpts[tid] = pts[t * 72 + tid];
  __syncthreads();
  for (int p = 0; p < 36; ++p){
    float fx = lpts[p*2]   * 64.f - 0.5f;
    float fy = lpts[p*2+1] * 64.f - 0.5f;
    float x0f = floorf(fx), y0f = floorf(fy);
    float wx = fx - x0f, wy = fy - y0f;
    int x0 = (int)x0f, y0 = (int)y0f;
    float acc = 0.f;
    #pragma unroll
    for (int dy = 0; dy < 2; ++dy){
      #pragma unroll
      for (int dx = 0; dx < 2; ++dx){
        int xi = x0 + dx, yi = y0 + dy;
        bool valid = (xi >= 0) & (xi < 64) & (yi >= 0) & (yi < 64);
        int xc = min(max(xi, 0), 63), yc = min(max(yi, 0), 63);
        float w = (dx ? wx : 1.f - wx) * (dy ? wy : 1.f - wy);
        float v = bf2f(imgT[(((size_t)(b * 64 + yc)) * 64 + xc) * 256 + tid]);
        acc += v * (valid ? w : 0.f);
      }
    }
    sampled48[(size_t)t * 12288 + p * 256 + tid] = f2bf(acc);
  }
  #pragma unroll
  for (int p = 36; p < 48; ++p)
    sampled48[(size_t)t * 12288 + p * 256 + tid] = 0;
}

// ---------------- kernel 4a: cm params in fragment order ----------------
// grid (64 f-tiles, 8 token-tiles of 128). Per (nq4,mt): 64 tokens x 256 f tile;
// writes 512B contiguous per token.
__global__ __launch_bounds__(256) void k_params_cm(
    const float* __restrict__ hbuf, const float* __restrict__ w2f,
    const float* __restrict__ b2f, unsigned short* __restrict__ params3)
{
  __shared__ __align__(16) unsigned short Bs[256][72];  // [f-row][k^swz]
  __shared__ __align__(16) unsigned short As[64][72];   // [token][k]
  __shared__ __align__(16) unsigned short Os[64][264];  // [token][f-local]
  const int tid = threadIdx.x, lane = tid & 63, wave = tid >> 6;
  const int wm = wave >> 1, wn = wave & 1;
  const int l15 = lane & 15;
  const int NT = blockIdx.x;
  const int t0 = blockIdx.y * 128;
  for (int nq4 = 0; nq4 < 4; ++nq4){
    const int F0 = NT * 1024 + nq4 * 256;
    {
      const float* src = w2f + (size_t)(F0 + tid) * 64;
      const int swz = ((tid >> 3) & 7) << 3;
      #pragma unroll
      for (int k8 = 0; k8 < 64; k8 += 8){
        unsigned short tmp[8];
        #pragma unroll
        for (int i = 0; i < 8; ++i) tmp[i] = f2bf(src[k8 + i]);
        *(bf16x8*)&Bs[tid][k8 ^ swz] = *(const bf16x8*)tmp;
      }
    }
    float bv[8];
    #pragma unroll
    for (int jf = 0; jf < 8; ++jf)
      bv[jf] = b2f[F0 + wn*128 + jf*16 + l15];
    __syncthreads();
    for (int mt = 0; mt < 2; ++mt){
      { int m = tid >> 2, k4 = (tid & 3) * 16;
        const float* hp = hbuf + (size_t)(t0 + mt*64 + m) * 64 + k4;
        #pragma unroll
        for (int i = 0; i < 16; ++i) As[m][k4 + i] = f2bf(hp[i]);
      }
      __syncthreads();
      f32x4 acc[2][8] = {};
      #pragma unroll
      for (int ks = 0; ks < 2; ++ks){
        int kb = ks * 32 + (lane >> 4) * 8;
        bf16x8 a[2], b[8];
        #pragma unroll
        for (int i = 0; i < 2; ++i) a[i] = *(const bf16x8*)&As[wm*32 + i*16 + l15][kb];
        #pragma unroll
        for (int jf = 0; jf < 8; ++jf){
          int row = wn*128 + jf*16 + l15;
          b[jf] = *(const bf16x8*)&Bs[row][kb ^ (((row >> 3) & 7) << 3)];
        }
        #pragma unroll
        for (int i = 0; i < 2; ++i)
          #pragma unroll
          for (int jf = 0; jf < 8; ++jf) acc[i][jf] = mfma16(a[i], b[jf], acc[i][jf]);
      }
      #pragma unroll
      for (int i = 0; i < 2; ++i)
        #pragma unroll
        for (int jf = 0; jf < 8; ++jf){
          int col = wn*128 + jf*16 + l15;
          #pragma unroll
          for (int r = 0; r < 4; ++r){
            int row = wm*32 + i*16 + (lane >> 4) * 4 + r;
            Os[row][col] = f2bf(acc[i][jf][r] + bv[jf]);
          }
        }
      __syncthreads();
      { int row = tid >> 2, c0 = (tid & 3) * 64;
        size_t g = (size_t)(t0 + mt*64 + row) * 65536 + F0 + c0;
        #pragma unroll
        for (int q = 0; q < 64; q += 8)
          *(bf16x8*)(params3 + g + q) = *(const bf16x8*)&Os[row][c0 + q];
      }
      __syncthreads();
    }
  }
}

// ---------------- kernel 4b: sm tail in blocked layout (21 chunks) ----------------
__global__ __launch_bounds__(256) void k_params_sm(
    const float* __restrict__ hbuf, const float* __restrict__ w2f,
    const float* __restrict__ b2f, unsigned short* __restrict__ params3)
{
  __shared__ __align__(16) unsigned short Bs[64][72];
  __shared__ __align__(16) unsigned short As[64][72];
  __shared__ __align__(16) unsigned short Os[64][72];
  const int tid = threadIdx.x, lane = tid & 63, wave = tid >> 6;
  const int wm = wave >> 1, wn = wave & 1;
  const int nc = 1024 + blockIdx.x;
  {
    int nl = tid >> 2, k0 = (tid & 3) * 16;
    const float* wp = w2f + ((size_t)nc * 64 + nl) * 64 + k0;
    const int swz = ((nl >> 3) & 7) << 3;
    #pragma unroll
    for (int i = 0; i < 16; ++i)
      Bs[nl][(k0 + i) ^ swz] = f2bf(wp[i]);
  }
  float bv[2];
  #pragma unroll
  for (int j = 0; j < 2; ++j)
    bv[j] = b2f[nc * 64 + wn*32 + j*16 + (lane & 15)];
  __syncthreads();
  for (int mt = 0; mt < 16; ++mt){
    int m0 = mt * 64;
    { int m = tid >> 2, kb4 = (tid & 3) * 16;
      const float* hp = hbuf + (m0 + m) * 64 + kb4;
      #pragma unroll
      for (int i = 0; i < 16; ++i) As[m][kb4 + i] = f2bf(hp[i]);
    }
    __syncthreads();
    f32x4 acc[2][2] = {};
    #pragma unroll
    for (int ks = 0; ks < 2; ++ks){
      int kb = ks * 32 + (lane >> 4) * 8;
      bf16x8 a[2], bb[2];
      #pragma unroll
      for (int i = 0; i < 2; ++i) a[i] = *(const bf16x8*)&As[wm*32 + i*16 + (lane & 15)][kb];
      #pragma unroll
      for (int j = 0; j < 2; ++j){
        int n = wn*32 + j*16 + (lane & 15);
        bb[j] = *(const bf16x8*)&Bs[n][kb ^ (((n >> 3) & 7) << 3)];
      }
      #pragma unroll
      for (int i = 0; i < 2; ++i)
        #pragma unroll
        for (int j = 0; j < 2; ++j) acc[i][j] = mfma16(a[i], bb[j], acc[i][j]);
    }
    #pragma unroll
    for (int i = 0; i < 2; ++i)
      #pragma unroll
      for (int j = 0; j < 2; ++j){
        int cl = wn*32 + j*16 + (lane & 15);
        #pragma unroll
        for (int r = 0; r < 4; ++r){
          int rl = wm*32 + i*16 + (lane >> 4) * 4 + r;
          Os[rl][cl] = f2bf(acc[i][j][r] + bv[j]);
        }
      }
    __syncthreads();
    { int rl = tid >> 2, c0 = (tid & 3) * 16;
      size_t gbase = ((size_t)nc * 1024 + m0 + rl) * 64 + c0;
      *(bf16x8*)(params3 + gbase)     = *(const bf16x8*)&Os[rl][c0];
      *(bf16x8*)(params3 + gbase + 8) = *(const bf16x8*)&Os[rl][c0 + 8];
    }
    __syncthreads();
  }
}

// ---------------- kernel 5: per-token adaptive mixing ----------------
// phase-1 B-frags stream 1KB-contiguous from fragment-ordered params3;
// S staged in LDS; O1T aliases Ss after phase 1.
__global__ __launch_bounds__(256) void k_mixtoken(
    const unsigned short* __restrict__ sampled48,
    const unsigned short* __restrict__ params3,
    const float* __restrict__ m_beta, const float* __restrict__ s_beta,
    unsigned short* __restrict__ out2)
{
  __shared__ __align__(16) unsigned short smem[21888];
  unsigned short (*Ss)[264] = (unsigned short (*)[264])smem;           // [48][256+8]
  unsigned short (*O1T)[72] = (unsigned short (*)[72])smem;            // [256][64+8] (aliases Ss)
  unsigned short (*Sm)[72]  = (unsigned short (*)[72])(smem + 18432);  // [48][64+8]
  const int t = blockIdx.x, tid = threadIdx.x, lane = tid & 63, wave = tid >> 6;
  const int l15 = lane & 15, kb = (lane >> 4) * 8;
  // fused zero+stage of Sm (no race: one linear map)
  for (int idx = tid; idx < 3456; idx += 256){
    int o = idx / 72, p = idx % 72;
    unsigned short v = 0;
    if (o < 36 && p < 36){
      int n = 65536 + o * 36 + p;
      v = params3[(size_t)(n >> 6) * 65536 + (size_t)t * 64 + (n & 63)];
    }
    smem[18432 + idx] = v;
  }
  // stage Ss [48][256] (rows 36-47 are zeros in sampled48)
  const unsigned short* sp = sampled48 + (size_t)t * 12288;
  #pragma unroll
  for (int it = 0; it < 6; ++it){
    int slot = it * 256 + tid;
    int p = slot >> 5, c8 = (slot & 31) << 3;
    *(bf16x8*)&Ss[p][c8] = *(const bf16x8*)(sp + p * 256 + c8);
  }
  __syncthreads();
  // ---- phase 1: out1 = S @ cm; B-frags stream from global ----
  const unsigned short* pb = params3 + (size_t)t * 65536 + wave * 2048 + lane * 8;
  f32x4 acc[3][4] = {};
  #pragma unroll 2
  for (int cc = 0; cc < 8; ++cc){
    bf16x8 a[3], bfr[4];
    #pragma unroll
    for (int j = 0; j < 4; ++j)
      bfr[j] = *(const bf16x8*)(pb + cc * 8192 + j * 512);
    #pragma unroll
    for (int i = 0; i < 3; ++i)
      a[i] = *(const bf16x8*)&Ss[i*16 + l15][cc*32 + kb];
    #pragma unroll
    for (int i = 0; i < 3; ++i)
      #pragma unroll
      for (int j = 0; j < 4; ++j) acc[i][j] = mfma16(a[i], bfr[j], acc[i][j]);
  }
  __syncthreads();   // Ss reads done; smem becomes O1T
  // zero O1T (cols 36-63 must be zero; pad never read)
  {
    const bf16x8 z = {};
    #pragma unroll
    for (int i = 0; i < 9; ++i)
      *(bf16x8*)&smem[(i * 256 + tid) * 8] = z;
  }
  __syncthreads();
  {
    #pragma unroll
    for (int i = 0; i < 3; ++i){
      int p = i*16 + ((lane >> 4) << 2);
      if (p < 36){
        #pragma unroll
        for (int j = 0; j < 4; ++j){
          int d = wave*64 + j*16 + l15;
          float mb = m_beta[d];
          unsigned short* dst = &O1T[d][p];
          #pragma unroll
          for (int r = 0; r < 4; ++r) dst[r] = f2bf(gelu_f(acc[i][j][r] + mb));
        }
      }
    }
  }
  __syncthreads();
  // ---- phase 2: out2 = sm @ out1 ----
  f32x4 acc2[3][4] = {};
  #pragma unroll
  for (int ks = 0; ks < 2; ++ks){
    int kb2 = ks * 32 + (lane >> 4) * 8;
    bf16x8 a[3], bfr[4];
    #pragma unroll
    for (int i = 0; i < 3; ++i) a[i] = *(const bf16x8*)&Sm[i*16 + l15][kb2];
    #pragma unroll
    for (int j = 0; j < 4; ++j) bfr[j] = *(const bf16x8*)&O1T[wave*64 + j*16 + l15][kb2];
    #pragma unroll
    for (int i = 0; i < 3; ++i)
      #pragma unroll
      for (int j = 0; j < 4; ++j) acc2[i][j] = mfma16(a[i], bfr[j], acc2[i][j]);
  }
  unsigned short* o2 = out2 + (size_t)t * 9216;
  #pragma unroll
  for (int i = 0; i < 3; ++i){
    int ob = i*16 + ((lane >> 4) << 2);
    #pragma unroll
    for (int j = 0; j < 4; ++j){
      int d = wave*64 + j*16 + l15;
      #pragma unroll
      for (int r = 0; r < 4; ++r){
        int o = ob + r;
        if (o < 36) o2[o * 256 + d] = f2bf(gelu_f(acc2[i][j][r] + s_beta[o]));
      }
    }
  }
}

// ---------------- generic GEMM: C = act(A @ W + bias) (+resid) ----------------
template<int AK, int ACT, int RES, int OUTB>
__global__ __launch_bounds__(256) void k_gemm(
    const void* __restrict__ Ap, const float* __restrict__ W,
    const float* __restrict__ bias, const float* __restrict__ resid,
    void* __restrict__ Cp, int M, int N, int K)
{
  __shared__ __align__(16) unsigned short As[64][40];  // [m][k]
  __shared__ __align__(16) unsigned short Bs[64][40];  // [n][k^swz]
  const int tid = threadIdx.x, lane = tid & 63, wave = tid >> 6;
  const int wm = wave >> 1, wn = wave & 1;
  const int n0 = blockIdx.x * 64, m0 = blockIdx.y * 64;
  f32x4 acc[2][2] = {};
  for (int kk = 0; kk < K; kk += 32){
    { int m = tid >> 2, k4 = (tid & 3) * 8;
      if (AK == 0){
        const float* ap = (const float*)Ap + (size_t)(m0 + m) * K + kk + k4;
        #pragma unroll
        for (int i = 0; i < 8; ++i) As[m][k4 + i] = f2bf(ap[i]);
      } else {
        const unsigned short* ap = (const unsigned short*)Ap + (size_t)(m0 + m) * K + kk + k4;
        *(bf16x8*)&As[m][k4] = *(const bf16x8*)ap;
      }
    }
    { int kq = tid >> 3, n8 = (tid & 7) * 8;
      const float* wp = W + (size_t)(kk + kq) * N + n0 + n8;
      #pragma unroll
      for (int i = 0; i < 8; ++i){
        int n = n8 + i;
        Bs[n][kq ^ (((n >> 3) & 3) << 3)] = f2bf(wp[i]);
      }
    }
    __syncthreads();
    const int kb = (lane >> 4) * 8;
    bf16x8 a[2], bfr[2];
    #pragma unroll
    for (int i = 0; i < 2; ++i) a[i] = *(const bf16x8*)&As[wm*32 + i*16 + (lane & 15)][kb];
    #pragma unroll
    for (int j = 0; j < 2; ++j){
      int n = wn*32 + j*16 + (lane & 15);
      bfr[j] = *(const bf16x8*)&Bs[n][kb ^ (((n >> 3) & 3) << 3)];
    }
    #pragma unroll
    for (int i = 0; i < 2; ++i)
      #pragma unroll
      for (int j = 0; j < 2; ++j) acc[i][j] = mfma16(a[i], bfr[j], acc[i][j]);
    __syncthreads();
  }
  #pragma unroll
  for (int i = 0; i < 2; ++i)
    #pragma unroll
    for (int j = 0; j < 2; ++j){
      int col = n0 + wn*32 + j*16 + (lane & 15);
      float bv = bias[col];
      #pragma unroll
      for (int r = 0; r < 4; ++r){
        int row = m0 + wm*32 + i*16 + (lane >> 4) * 4 + r;
        float v = acc[i][j][r] + bv;
        if (ACT == 1) v = gelu_f(v);
        if (RES) v += resid[(size_t)row * N + col];
        if (OUTB) ((unsigned short*)Cp)[(size_t)row * N + col] = f2bf(v);
        else      ((float*)Cp)[(size_t)row * N + col] = v;
      }
    }
}

// ---------------- split-K GEMM: part[z][M][N] = A[:, z*KS:(z+1)*KS] @ W[z*KS:...] ----
template<int AK>
__global__ __launch_bounds__(256) void k_gemm_sk(
    const void* __restrict__ Ap, const float* __restrict__ W,
    float* __restrict__ part, int M, int N, int K, int KS)
{
  __shared__ __align__(16) unsigned short As[64][40];  // [m][k]
  __shared__ __align__(16) unsigned short Bs[64][40];  // [n][k^swz]
  const int tid = threadIdx.x, lane = tid & 63, wave = tid >> 6;
  const int wm = wave >> 1, wn = wave & 1;
  const int n0 = blockIdx.x * 64, m0 = blockIdx.y * 64;
  const int kbase = blockIdx.z * KS;
  f32x4 acc[2][2] = {};
  for (int kq = 0; kq < KS; kq += 32){
    int kk = kbase + kq;
    { int m = tid >> 2, k4 = (tid & 3) * 8;
      if (AK == 0){
        const float* ap = (const float*)Ap + (size_t)(m0 + m) * K + kk + k4;
        #pragma unroll
        for (int i = 0; i < 8; ++i) As[m][k4 + i] = f2bf(ap[i]);
      } else {
        const unsigned short* ap = (const unsigned short*)Ap + (size_t)(m0 + m) * K + kk + k4;
        *(bf16x8*)&As[m][k4] = *(const bf16x8*)ap;
      }
    }
    { int kr = tid >> 3, n8 = (tid & 7) * 8;
      const float* wp = W + (size_t)(kk + kr) * N + n0 + n8;
      #pragma unroll
      for (int i = 0; i < 8; ++i){
        int n = n8 + i;
        Bs[n][kr ^ (((n >> 3) & 3) << 3)] = f2bf(wp[i]);
      }
    }
    __syncthreads();
    const int kb = (lane >> 4) * 8;
    bf16x8 a[2], bfr[2];
    #pragma unroll
    for (int i = 0; i < 2; ++i) a[i] = *(const bf16x8*)&As[wm*32 + i*16 + (lane & 15)][kb];
    #pragma unroll
    for (int j = 0; j < 2; ++j){
      int n = wn*32 + j*16 + (lane & 15);
      bfr[j] = *(const bf16x8*)&Bs[n][kb ^ (((n >> 3) & 3) << 3)];
    }
    #pragma unroll
    for (int i = 0; i < 2; ++i)
      #pragma unroll
      for (int j = 0; j < 2; ++j) acc[i][j] = mfma16(a[i], bfr[j], acc[i][j]);
    __syncthreads();
  }
  float* pz = part + (size_t)blockIdx.z * M * N;
  #pragma unroll
  for (int i = 0; i < 2; ++i)
    #pragma unroll
    for (int j = 0; j < 2; ++j){
      int col = n0 + wn*32 + j*16 + (lane & 15);
      #pragma unroll
      for (int r = 0; r < 4; ++r){
        int row = m0 + wm*32 + i*16 + (lane >> 4) * 4 + r;
        pz[(size_t)row * N + col] = acc[i][j][r];
      }
    }
}

// ---------------- split-K reduce: out = sum_z part[z] + bias (+resid) ----------------
template<int RES>
__global__ __launch_bounds__(256) void k_reduce(
    const float* __restrict__ part, const float* __restrict__ bias,
    const float* __restrict__ resid, float* __restrict__ out,
    int total, int N, int SK)
{
  int i = blockIdx.x * 256 + threadIdx.x;
  if (i >= total) return;
  float s = 0.f;
  for (int z = 0; z < SK; ++z) s += part[(size_t)z * total + i];
  s += bias[i % N];
  if (RES) s += resid[i];
  out[i] = s;
}

// ---------------- fused split-K reduce + residual + LayerNorm ----------------
__global__ __launch_bounds__(256) void k_reduce_ln(
    const float* __restrict__ part, const float* __restrict__ bias,
    const float* __restrict__ resid,
    const float* __restrict__ g, const float* __restrict__ bb,
    float* __restrict__ emb_out, unsigned short* __restrict__ ln_out, int SK)
{
  __shared__ float red[4];
  const int t = blockIdx.x, tid = threadIdx.x;
  const int i = t * 256 + tid;
  float s = 0.f;
  for (int z = 0; z < SK; ++z) s += part[(size_t)z * 262144 + i];
  s += bias[tid] + resid[i];
  emb_out[i] = s;
  float mean = block_sum(s, red, tid) * (1.f / 256.f);
  float d = s - mean;
  float var = block_sum(d * d, red, tid) * (1.f / 256.f);
  ln_out[i] = f2bf(d * rsqrtf(var + 1e-5f) * g[tid] + bb[tid]);
}

// ---------------- attention: one (b,h) per block ----------------
__global__ __launch_bounds__(64) void k_attn(const float* __restrict__ qkv,
                                             float* __restrict__ attno)
{
  __shared__ float qs[64][33], ksm[64][33], vsm[64][33];
  const int blk = blockIdx.x, lane = threadIdx.x;
  const int b = blk >> 3, h = blk & 7;
  for (int idx = lane; idx < 2048; idx += 64){
    int row = idx >> 5, d = idx & 31;
    const float* base = qkv + (size_t)(b * 64 + row) * 768 + h * 32 + d;
    qs[row][d] = base[0]; ksm[row][d] = base[256]; vsm[row][d] = base[512];
  }
  __syncthreads();
  float qr[32];
  #pragma unroll
  for (int d = 0; d < 32; ++d) qr[d] = qs[lane][d];
  float s[64]; float mx = -1e30f;
  for (int m = 0; m < 64; ++m){
    float dot = 0.f;
    #pragma unroll
    for (int d = 0; d < 32; ++d) dot += qr[d] * ksm[m][d];
    dot *= 0.17677669529663687f;  // 32^-0.5
    s[m] = dot; mx = fmaxf(mx, dot);
  }
  float sum = 0.f;
  for (int m = 0; m < 64; ++m){ s[m] = expf(s[m] - mx); sum += s[m]; }
  float inv = 1.f / sum;
  float o[32] = {};
  for (int m = 0; m < 64; ++m){
    float p = s[m] * inv;
    #pragma unroll
    for (int d = 0; d < 32; ++d) o[d] += p * vsm[m][d];
  }
  float* dst = attno + (size_t)(b * 64 + lane) * 256 + h * 32;
  #pragma unroll
  for (int d = 0; d < 32; ++d) dst[d] = o[d];
}

__global__ void k_fill(float* p, int n, float v){
  int i = blockIdx.x * 256 + threadIdx.x;
  if (i < n) p[i] = v;
}

// ---------------- launch ----------------
extern "C" void kernel_launch(void* const* d_in, const int* in_sizes, int n_in,
                              void* d_out, int out_size, void* d_ws, size_t ws_size,
                              hipStream_t stream)
{
  const float* img      = (const float*)d_in[0];
  const float* embed    = (const float*)d_in[1];
  const float* roi      = (const float*)d_in[2];
  const float* ln_adj_g = (const float*)d_in[3];
  const float* ln_adj_b = (const float*)d_in[4];
  const float* w_adj    = (const float*)d_in[5];
  const float* ln_off_g = (const float*)d_in[6];
  const float* ln_off_b = (const float*)d_in[7];
  const float* w_off    = (const float*)d_in[8];
  const float* off_bias = (const float*)d_in[9];
  const float* pg_ln_g  = (const float*)d_in[10];
  const float* pg_ln_b  = (const float*)d_in[11];
  const float* pg_w1    = (const float*)d_in[12];
  const float* pg_b1    = (const float*)d_in[13];
  const float* pg_w2    = (const float*)d_in[14];
  const float* pg_b2    = (const float*)d_in[15];
  const float* m_beta   = (const float*)d_in[16];
  const float* s_beta   = (const float*)d_in[17];
  const float* mix_w    = (const float*)d_in[18];
  const float* mix_b    = (const float*)d_in[19];
  const float* ln1_g    = (const float*)d_in[20];
  const float* ln1_b    = (const float*)d_in[21];
  const float* qkv_w    = (const float*)d_in[22];
  const float* qkv_b    = (const float*)d_in[23];
  const float* proj_w   = (const float*)d_in[24];
  const float* proj_b   = (const float*)d_in[25];
  const float* ln2_g    = (const float*)d_in[26];
  const float* ln2_b    = (const float*)d_in[27];
  const float* fc1_w    = (const float*)d_in[28];
  const float* fc1_b    = (const float*)d_in[29];
  const float* fc2_w    = (const float*)d_in[30];
  const float* fc2_b    = (const float*)d_in[31];

  char* ws = (char*)d_ws;
  float*          pts       = (float*)         (ws + 0);          //   294912
  float*          hbuf      = (float*)         (ws + 294912);     //   262144
  // region A (sequential use): w2f (17121280) then imgT (33554432)
  float*          w2f       = (float*)         (ws + 557056);
  unsigned short* imgT      = (unsigned short*)(ws + 557056);
  unsigned short* sampled48 = (unsigned short*)(ws + 34111488);   // 25165824
  unsigned short* params3   = (unsigned short*)(ws + 59277312);   // 136970240 (1045*65536*2)
  unsigned short* out2      = (unsigned short*)(ws + 196247552);  // 18874368 -> 215121920
  float*          b2f       = (float*)         (ws + 215121920);  // 267520
  // aliased into params3 region (dead after k_mixtoken):
  char*           pr        = ws + 59277312;
  float*          part_mix  = (float*)(pr + 0);          // 16777216
  float*          part_smll = (float*)(pr + 16777216);   //  4194304
  unsigned short* h1        = (unsigned short*)(pr + 20971520); // 2097152
  float*          embed1    = (float*)(pr + 23068672);   //  1048576
  float*          embed2    = (float*)(pr + 24117248);   //  1048576
  unsigned short* xln1      = (unsigned short*)(pr + 25165824); // 524288
  unsigned short* xln2      = (unsigned short*)(pr + 25690112); // 524288
  float*          qkvb      = (float*)(pr + 26214400);   //  3145728
  float*          attno     = (float*)(pr + 29360128);   //  1048576
  const size_t WS_NEEDED = 215389440;
  if (ws_size < WS_NEEDED){
    k_fill<<<(out_size + 255) / 256, 256, 0, stream>>>((float*)d_out, out_size, 12345.0f);
    return;
  }

  float* out = (float*)d_out;

  k_prep<<<1024, 256, 0, stream>>>(embed, roi, ln_adj_g, ln_adj_b, w_adj,
                                   ln_off_g, ln_off_b, w_off, off_bias,
                                   pg_ln_g, pg_ln_b, pg_w1, pg_b1, pts, hbuf);
  k_w2t<<<1045, 256, 0, stream>>>(pg_w2, pg_b2, w2f, b2f);
  k_params_cm<<<dim3(64, 8), 256, 0, stream>>>(hbuf, w2f, b2f, params3);
  k_params_sm<<<21, 256, 0, stream>>>(hbuf, w2f, b2f, params3);
  k_transpose<<<1024, 256, 0, stream>>>(img, imgT);   // overwrites w2f region (dead)
  k_sample<<<1024, 256, 0, stream>>>(imgT, pts, sampled48);
  k_mixtoken<<<1024, 256, 0, stream>>>(sampled48, params3, m_beta, s_beta, out2);
  // embed1 = embed + out2 @ mix_w + mix_b   (split-K: 9216 = 16 x 576), fused LN1
  k_gemm_sk<1><<<dim3(4,16,16), 256, 0, stream>>>(out2, mix_w, part_mix, 1024, 256, 9216, 576);
  k_reduce_ln<<<1024, 256, 0, stream>>>(part_mix, mix_b, embed, ln1_g, ln1_b, embed1, xln1, 16);
  k_gemm<1,0,0,0><<<dim3(12,16), 256, 0, stream>>>(xln1, qkv_w, qkv_b, nullptr, qkvb, 1024, 768, 256);
  k_attn<<<128, 64, 0, stream>>>(qkvb, attno);
  // embed2 = embed1 + attno @ proj_w + proj_b (split-K: 256 = 4 x 64), fused LN2
  k_gemm_sk<0><<<dim3(4,16,4), 256, 0, stream>>>(attno, proj_w, part_smll, 1024, 256, 256, 64);
  k_reduce_ln<<<1024, 256, 0, stream>>>(part_smll, proj_b, embed1, ln2_g, ln2_b, embed2, xln2, 4);
  k_gemm<1,1,0,1><<<dim3(16,16), 256, 0, stream>>>(xln2, fc1_w, fc1_b, nullptr, h1, 1024, 1024, 256);
  // out = embed2 + h1 @ fc2_w + fc2_b   (split-K: 1024 = 4 x 256)
  k_gemm_sk<1><<<dim3(4,16,4), 256, 0, stream>>>(h1, fc2_w, part_smll, 1024, 256, 1024, 256);
  k_reduce<1><<<1024, 256, 0, stream>>>(part_smll, fc2_b, embed2, out, 262144, 256, 4);
}

// Round 7
// 288.469 us; speedup vs baseline: 1.2427x; 1.2427x over previous
//
#include <hip/hip_runtime.h>
#include <cstdint>

#define DEV __device__ __forceinline__

typedef __attribute__((ext_vector_type(8))) short bf16x8;
typedef __attribute__((ext_vector_type(4))) float f32x4;

DEV unsigned short f2bf(float x){
  union { float f; unsigned u; } c; c.f = x;
  unsigned r = c.u + 0x7fffu + ((c.u >> 16) & 1u);
  return (unsigned short)(r >> 16);
}
DEV float bf2f(unsigned short h){
  union { unsigned u; float f; } c; c.u = ((unsigned)h) << 16;
  return c.f;
}
DEV float gelu_f(float x){ return 0.5f * x * (1.f + erff(x * 0.70710678118654752440f)); }

DEV f32x4 mfma16(bf16x8 a, bf16x8 b, f32x4 c){
  return __builtin_amdgcn_mfma_f32_16x16x32_bf16(a, b, c, 0, 0, 0);
}

// block_sum: 256 threads (4 waves)
DEV float block_sum(float v, float* red, int tid){
  #pragma unroll
  for (int o = 32; o > 0; o >>= 1) v += __shfl_down(v, o);
  if ((tid & 63) == 0) red[tid >> 6] = v;
  __syncthreads();
  float s = red[0] + red[1] + red[2] + red[3];
  __syncthreads();
  return s;
}

// ---------------- constants ----------------
// B=16 N=64 D=256 CI=256 H=W=64 P=36 HEADS=8 HD=32 HID=1024 TOTAL=66832 T=1024
// params3 blocked layout: element n of token t lives at
//   params3[(n>>6)*65536 + t*64 + (n&63)]   (nc-major, then token, then off)

// ---------------- kernel 1: per-token prep ----------------
__global__ __launch_bounds__(256) void k_prep(
    const float* __restrict__ embed, const float* __restrict__ roi,
    const float* __restrict__ g_adj, const float* __restrict__ b_adj, const float* __restrict__ w_adj,
    const float* __restrict__ g_off, const float* __restrict__ b_off, const float* __restrict__ w_off,
    const float* __restrict__ off_bias,
    const float* __restrict__ g_pg, const float* __restrict__ b_pg,
    const float* __restrict__ w_pg1, const float* __restrict__ b_pg1,
    float* __restrict__ pts, float* __restrict__ hbuf)
{
  __shared__ float red[4];
  __shared__ float xln[256];
  __shared__ float offs[72];
  __shared__ float lg[4];
  __shared__ float stat[8];
  const int t = blockIdx.x, tid = threadIdx.x;
  float e = embed[t * 256 + tid];
  float mean = block_sum(e, red, tid) * (1.f / 256.f);
  float dv = e - mean;
  float var = block_sum(dv * dv, red, tid) * (1.f / 256.f);
  xln[tid] = dv * rsqrtf(var + 1e-5f);
  __syncthreads();
  if (tid < 4){
    float a0 = 0.f, a1 = 0.f, a2 = 0.f, a3 = 0.f;
    #pragma unroll 4
    for (int c = 0; c < 256; c += 4){
      a0 += (xln[c+0] * g_adj[c+0] + b_adj[c+0]) * w_adj[(c+0) * 4 + tid];
      a1 += (xln[c+1] * g_adj[c+1] + b_adj[c+1]) * w_adj[(c+1) * 4 + tid];
      a2 += (xln[c+2] * g_adj[c+2] + b_adj[c+2]) * w_adj[(c+2) * 4 + tid];
      a3 += (xln[c+3] * g_adj[c+3] + b_adj[c+3]) * w_adj[(c+3) * 4 + tid];
    }
    lg[tid] = (a0 + a1) + (a2 + a3);
  } else if (tid < 76){
    int j = tid - 4;
    float a0 = 0.f, a1 = 0.f, a2 = 0.f, a3 = 0.f;
    #pragma unroll 4
    for (int c = 0; c < 256; c += 4){
      a0 += (xln[c+0] * g_off[c+0] + b_off[c+0]) * w_off[(c+0) * 72 + j];
      a1 += (xln[c+1] * g_off[c+1] + b_off[c+1]) * w_off[(c+1) * 72 + j];
      a2 += (xln[c+2] * g_off[c+2] + b_off[c+2]) * w_off[(c+2) * 72 + j];
      a3 += (xln[c+3] * g_off[c+3] + b_off[c+3]) * w_off[(c+3) * 72 + j];
    }
    offs[j] = (a0 + a1) + (a2 + a3) + off_bias[j];
  } else if (tid < 140){
    int j = tid - 76;
    float a0 = 0.f, a1 = 0.f, a2 = 0.f, a3 = 0.f;
    #pragma unroll 4
    for (int c = 0; c < 256; c += 4){
      a0 += (xln[c+0] * g_pg[c+0] + b_pg[c+0]) * w_pg1[(c+0) * 64 + j];
      a1 += (xln[c+1] * g_pg[c+1] + b_pg[c+1]) * w_pg1[(c+1) * 64 + j];
      a2 += (xln[c+2] * g_pg[c+2] + b_pg[c+2]) * w_pg1[(c+2) * 64 + j];
      a3 += (xln[c+3] * g_pg[c+3] + b_pg[c+3]) * w_pg1[(c+3) * 64 + j];
    }
    hbuf[t * 64 + j] = (a0 + a1) + (a2 + a3) + b_pg1[j];
  }
  __syncthreads();
  if (tid == 0){
    float x0 = roi[t*4+0], y0 = roi[t*4+1], x1 = roi[t*4+2], y1 = roi[t*4+3];
    float cx = (x0 + x1) * 0.5f, cy = (y0 + y1) * 0.5f;
    float w = fabsf(x1 - x0), hh = fabsf(y1 - y0);
    cx += lg[0] * w; cy += lg[1] * hh;
    w *= expf(lg[2]); hh *= expf(lg[3]);
    stat[0] = cx; stat[1] = cy; stat[2] = w; stat[3] = hh;
  }
  if (tid < 2){
    float mu = 0.f;
    for (int p = 0; p < 36; ++p) mu += offs[p*2 + tid];
    mu *= (1.f / 36.f);
    float v2 = 0.f;
    for (int p = 0; p < 36; ++p){ float d = offs[p*2 + tid] - mu; v2 += d * d; }
    float sd = sqrtf(v2 * (1.f / 35.f)) + 1e-7f;   // ddof=1
    stat[4 + tid] = mu; stat[6 + tid] = 1.f / (3.f * sd);
  }
  __syncthreads();
  if (tid < 72){
    int c = tid & 1;
    pts[t * 72 + tid] = stat[c] + (offs[tid] - stat[4 + c]) * stat[6 + c] * stat[2 + c];
  }
}

// ---------------- kernel 2: img [B,C,H,W] f32 -> [B,H,W,C] bf16 ----------------
__global__ __launch_bounds__(256) void k_transpose(const float* __restrict__ img,
                                                   unsigned short* __restrict__ imgT)
{
  __shared__ float tile[128][65];
  const int blk = blockIdx.x, tid = threadIdx.x;
  const int b = blk >> 6, y = blk & 63;
  for (int half = 0; half < 2; ++half){
    int c_loc = tid >> 1, x0 = (tid & 1) * 32;
    const float* src = img + (((size_t)(b * 256 + half * 128 + c_loc)) * 64 + y) * 64 + x0;
    #pragma unroll
    for (int i = 0; i < 32; ++i) tile[c_loc][x0 + i] = src[i];
    __syncthreads();
    int c = tid & 127, xh = tid >> 7;
    size_t obase = ((size_t)(b * 64 + y)) * 64 * 256 + half * 128 + c;
    for (int xx = 0; xx < 64; xx += 2){
      int x = xx + xh;
      imgT[obase + (size_t)x * 256] = f2bf(tile[c][x]);
    }
    __syncthreads();
  }
}

// ---------------- kernel 3: bilinear sample -> sampled [T,36,256] bf16 ----------------
__global__ __launch_bounds__(256) void k_sample(const unsigned short* __restrict__ imgT,
                                                const float* __restrict__ pts,
                                                unsigned short* __restrict__ sampled)
{
  __shared__ float lpts[72];
  const int t = blockIdx.x, tid = threadIdx.x;
  const int b = t >> 6;
  if (tid < 72) lpts[tid] = pts[t * 72 + tid];
  __syncthreads();
  for (int p = 0; p < 36; ++p){
    float fx = lpts[p*2]   * 64.f - 0.5f;
    float fy = lpts[p*2+1] * 64.f - 0.5f;
    float x0f = floorf(fx), y0f = floorf(fy);
    float wx = fx - x0f, wy = fy - y0f;
    int x0 = (int)x0f, y0 = (int)y0f;
    float acc = 0.f;
    #pragma unroll
    for (int dy = 0; dy < 2; ++dy){
      #pragma unroll
      for (int dx = 0; dx < 2; ++dx){
        int xi = x0 + dx, yi = y0 + dy;
        bool valid = (xi >= 0) & (xi < 64) & (yi >= 0) & (yi < 64);
        int xc = min(max(xi, 0), 63), yc = min(max(yi, 0), 63);
        float w = (dx ? wx : 1.f - wx) * (dy ? wy : 1.f - wy);
        float v = bf2f(imgT[(((size_t)(b * 64 + yc)) * 64 + xc) * 256 + tid]);
        acc += v * (valid ? w : 0.f);
      }
    }
    sampled[(size_t)t * 9216 + p * 256 + tid] = f2bf(acc);
  }
}

// ---------------- kernel 4: params3 = blocked(h @ pg_w2 + pg_b2)  (M=1024,K=64,N=66832)
// grid (1045); block nc computes all 1024 tokens for its 64-wide n-chunk.
// Writes are a single contiguous 128KB window per block: ((nc*1024)+m)*64 + off.
__global__ __launch_bounds__(256) void k_params(
    const float* __restrict__ hbuf, const float* __restrict__ w2,
    const float* __restrict__ b2, unsigned short* __restrict__ params3)
{
  __shared__ __align__(16) unsigned short Bs[64][72];  // [n][k^swz]
  __shared__ __align__(16) unsigned short As[64][72];  // [m][k]
  __shared__ __align__(16) unsigned short Os[64][72];  // output staging [m][n]
  const int tid = threadIdx.x, lane = tid & 63, wave = tid >> 6;
  const int wm = wave >> 1, wn = wave & 1;
  const int nc = blockIdx.x, n0 = nc * 64;
  {
    int k = tid >> 2, nb = (tid & 3) * 16;
    #pragma unroll
    for (int i = 0; i < 16; ++i){
      int n = nb + i, gn = n0 + n;
      float v = (gn < 66832) ? w2[(size_t)k * 66832 + gn] : 0.f;
      Bs[n][k ^ (((n >> 3) & 7) << 3)] = f2bf(v);
    }
  }
  float bv[2];
  #pragma unroll
  for (int j = 0; j < 2; ++j){
    int col = n0 + wn*32 + j*16 + (lane & 15);
    bv[j] = (col < 66832) ? b2[col] : 0.f;
  }
  __syncthreads();
  for (int mt = 0; mt < 16; ++mt){
    int m0 = mt * 64;
    { int m = tid >> 2, kb4 = (tid & 3) * 16;
      const float* hp = hbuf + (m0 + m) * 64 + kb4;
      #pragma unroll
      for (int i = 0; i < 16; ++i) As[m][kb4 + i] = f2bf(hp[i]);
    }
    __syncthreads();
    f32x4 acc[2][2] = {};
    #pragma unroll
    for (int ks = 0; ks < 2; ++ks){
      int kb = ks * 32 + (lane >> 4) * 8;
      bf16x8 a[2], bb[2];
      #pragma unroll
      for (int i = 0; i < 2; ++i) a[i] = *(const bf16x8*)&As[wm*32 + i*16 + (lane & 15)][kb];
      #pragma unroll
      for (int j = 0; j < 2; ++j){
        int n = wn*32 + j*16 + (lane & 15);
        bb[j] = *(const bf16x8*)&Bs[n][kb ^ (((n >> 3) & 7) << 3)];
      }
      #pragma unroll
      for (int i = 0; i < 2; ++i)
        #pragma unroll
        for (int j = 0; j < 2; ++j) acc[i][j] = mfma16(a[i], bb[j], acc[i][j]);
    }
    // stage tile in LDS: Os[m][n]
    #pragma unroll
    for (int i = 0; i < 2; ++i)
      #pragma unroll
      for (int j = 0; j < 2; ++j){
        int cl = wn*32 + j*16 + (lane & 15);
        #pragma unroll
        for (int r = 0; r < 4; ++r){
          int rl = wm*32 + i*16 + (lane >> 4) * 4 + r;
          Os[rl][cl] = f2bf(acc[i][j][r] + bv[j]);
        }
      }
    __syncthreads();
    // contiguous store: 8KB dense per tile, appended across the m-loop
    {
      int rl = tid >> 2, c0 = (tid & 3) * 16;
      size_t gbase = ((size_t)nc * 1024 + m0 + rl) * 64 + c0;
      *(bf16x8*)(params3 + gbase)     = *(const bf16x8*)&Os[rl][c0];
      *(bf16x8*)(params3 + gbase + 8) = *(const bf16x8*)&Os[rl][c0 + 8];
    }
    __syncthreads();
  }
}

// ---------------- kernel 5: per-token adaptive mixing (cm then sm), out2 [T,9216] bf16
// Staging of cm now uses bf16x8 vector loads (8 consecutive d at fixed c per load):
// element (c = cc*32+cl, d) lives at chunk q = cl*4 + (d>>6), offset d&63.
__global__ __launch_bounds__(256) void k_mixtoken(
    const unsigned short* __restrict__ sampled,
    const unsigned short* __restrict__ params3,
    const float* __restrict__ m_beta, const float* __restrict__ s_beta,
    unsigned short* __restrict__ out2)
{
  __shared__ __align__(16) unsigned short smem[23040];
  const int t = blockIdx.x, tid = threadIdx.x, lane = tid & 63, wave = tid >> 6;
  unsigned short (*Ss)[264] = (unsigned short (*)[264])smem;          // S [48][256+8]
  unsigned short (*Cs)[40]  = (unsigned short (*)[40])(smem + 12672); // cm chunk [256 d][32 k]
  const unsigned short* sp = sampled + (size_t)t * 9216;
  #pragma unroll
  for (int it = 0; it < 5; ++it){
    int slot = it * 256 + tid;
    if (slot < 1152){
      int p = slot >> 5, c8 = (slot & 31) << 3;
      *(bf16x8*)&Ss[p][c8] = *(const bf16x8*)(sp + p * 256 + c8);
    }
  }
  for (int r = 36; r < 48; ++r) Ss[r][tid] = 0;
  __syncthreads();
  f32x4 acc[3][4] = {};
  // vectorized staging decomposition (constant per thread)
  const int dh   = (tid >> 3) & 3;        // d high bits (d>>6)
  const int off0 = (tid & 7) * 8;         // 8-aligned offset within chunk
  const int d0   = dh * 64 + off0;        // base d of this thread's vectors
  const int sW   = ((d0 >> 3) & 3) << 3;  // write swizzle (same for all 8 rows)
  const unsigned short* ptok = params3 + (size_t)t * 64 + off0;
  for (int cc = 0; cc < 8; ++cc){
    // 4 vector loads per thread: cl = L*8 + (tid>>5), chunk = cc*128 + cl*4 + dh
    #pragma unroll
    for (int L = 0; L < 4; ++L){
      int cl = L * 8 + (tid >> 5);
      bf16x8 v = *(const bf16x8*)(ptok + ((size_t)(cc * 128 + cl * 4 + dh) << 16));
      int colw = cl ^ sW;
      #pragma unroll
      for (int j = 0; j < 8; ++j) Cs[d0 + j][colw] = ((unsigned short*)&v)[j];
    }
    __syncthreads();
    const int kb = (lane >> 4) * 8;
    bf16x8 a[3], bfr[4];
    #pragma unroll
    for (int i = 0; i < 3; ++i) a[i] = *(const bf16x8*)&Ss[i*16 + (lane & 15)][cc*32 + kb];
    #pragma unroll
    for (int j = 0; j < 4; ++j){
      int d = wave*64 + j*16 + (lane & 15);
      bfr[j] = *(const bf16x8*)&Cs[d][kb ^ (((d >> 3) & 3) << 3)];
    }
    #pragma unroll
    for (int i = 0; i < 3; ++i)
      #pragma unroll
      for (int j = 0; j < 4; ++j) acc[i][j] = mfma16(a[i], bfr[j], acc[i][j]);
    __syncthreads();
  }
  // repartition: O1T [256 d][64 p + 8], Sm [48 o][64 p + 8]
  unsigned short (*O1T)[72] = (unsigned short (*)[72])smem;
  unsigned short (*Sm)[72]  = (unsigned short (*)[72])(smem + 18432);
  for (int idx = tid; idx < 21888; idx += 256) smem[idx] = 0;
  __syncthreads();
  {
    for (int idx = tid; idx < 1296; idx += 256){
      int n = 65536 + idx;
      Sm[idx / 36][idx % 36] =
        params3[(size_t)(n >> 6) * 65536 + (size_t)t * 64 + (n & 63)];
    }
    #pragma unroll
    for (int i = 0; i < 3; ++i){
      int p = i*16 + ((lane >> 4) << 2);
      if (p < 36){
        #pragma unroll
        for (int j = 0; j < 4; ++j){
          int d = wave*64 + j*16 + (lane & 15);
          float mb = m_beta[d];
          unsigned short* dst = &O1T[d][p];
          #pragma unroll
          for (int r = 0; r < 4; ++r) dst[r] = f2bf(gelu_f(acc[i][j][r] + mb));
        }
      }
    }
  }
  __syncthreads();
  f32x4 acc2[3][4] = {};
  #pragma unroll
  for (int ks = 0; ks < 2; ++ks){
    int kb2 = ks * 32 + (lane >> 4) * 8;
    bf16x8 a[3], bfr[4];
    #pragma unroll
    for (int i = 0; i < 3; ++i) a[i] = *(const bf16x8*)&Sm[i*16 + (lane & 15)][kb2];
    #pragma unroll
    for (int j = 0; j < 4; ++j) bfr[j] = *(const bf16x8*)&O1T[wave*64 + j*16 + (lane & 15)][kb2];
    #pragma unroll
    for (int i = 0; i < 3; ++i)
      #pragma unroll
      for (int j = 0; j < 4; ++j) acc2[i][j] = mfma16(a[i], bfr[j], acc2[i][j]);
  }
  unsigned short* o2 = out2 + (size_t)t * 9216;
  #pragma unroll
  for (int i = 0; i < 3; ++i){
    int ob = i*16 + ((lane >> 4) << 2);
    #pragma unroll
    for (int j = 0; j < 4; ++j){
      int d = wave*64 + j*16 + (lane & 15);
      #pragma unroll
      for (int r = 0; r < 4; ++r){
        int o = ob + r;
        if (o < 36) o2[o * 256 + d] = f2bf(gelu_f(acc2[i][j][r] + s_beta[o]));
      }
    }
  }
}

// ---------------- generic GEMM: C = act(A @ W + bias) (+resid) ----------------
template<int AK, int ACT, int RES, int OUTB>
__global__ __launch_bounds__(256) void k_gemm(
    const void* __restrict__ Ap, const float* __restrict__ W,
    const float* __restrict__ bias, const float* __restrict__ resid,
    void* __restrict__ Cp, int M, int N, int K)
{
  __shared__ __align__(16) unsigned short As[64][40];  // [m][k]
  __shared__ __align__(16) unsigned short Bs[64][40];  // [n][k^swz]
  const int tid = threadIdx.x, lane = tid & 63, wave = tid >> 6;
  const int wm = wave >> 1, wn = wave & 1;
  const int n0 = blockIdx.x * 64, m0 = blockIdx.y * 64;
  f32x4 acc[2][2] = {};
  for (int kk = 0; kk < K; kk += 32){
    { int m = tid >> 2, k4 = (tid & 3) * 8;
      if (AK == 0){
        const float* ap = (const float*)Ap + (size_t)(m0 + m) * K + kk + k4;
        #pragma unroll
        for (int i = 0; i < 8; ++i) As[m][k4 + i] = f2bf(ap[i]);
      } else {
        const unsigned short* ap = (const unsigned short*)Ap + (size_t)(m0 + m) * K + kk + k4;
        *(bf16x8*)&As[m][k4] = *(const bf16x8*)ap;
      }
    }
    { int kq = tid >> 3, n8 = (tid & 7) * 8;
      const float* wp = W + (size_t)(kk + kq) * N + n0 + n8;
      #pragma unroll
      for (int i = 0; i < 8; ++i){
        int n = n8 + i;
        Bs[n][kq ^ (((n >> 3) & 3) << 3)] = f2bf(wp[i]);
      }
    }
    __syncthreads();
    const int kb = (lane >> 4) * 8;
    bf16x8 a[2], bfr[2];
    #pragma unroll
    for (int i = 0; i < 2; ++i) a[i] = *(const bf16x8*)&As[wm*32 + i*16 + (lane & 15)][kb];
    #pragma unroll
    for (int j = 0; j < 2; ++j){
      int n = wn*32 + j*16 + (lane & 15);
      bfr[j] = *(const bf16x8*)&Bs[n][kb ^ (((n >> 3) & 3) << 3)];
    }
    #pragma unroll
    for (int i = 0; i < 2; ++i)
      #pragma unroll
      for (int j = 0; j < 2; ++j) acc[i][j] = mfma16(a[i], bfr[j], acc[i][j]);
    __syncthreads();
  }
  #pragma unroll
  for (int i = 0; i < 2; ++i)
    #pragma unroll
    for (int j = 0; j < 2; ++j){
      int col = n0 + wn*32 + j*16 + (lane & 15);
      float bv = bias[col];
      #pragma unroll
      for (int r = 0; r < 4; ++r){
        int row = m0 + wm*32 + i*16 + (lane >> 4) * 4 + r;
        float v = acc[i][j][r] + bv;
        if (ACT == 1) v = gelu_f(v);
        if (RES) v += resid[(size_t)row * N + col];
        if (OUTB) ((unsigned short*)Cp)[(size_t)row * N + col] = f2bf(v);
        else      ((float*)Cp)[(size_t)row * N + col] = v;
      }
    }
}

// ---------------- split-K GEMM: part[z][M][N] = A[:, z*KS:(z+1)*KS] @ W[z*KS:...] ----
template<int AK>
__global__ __launch_bounds__(256) void k_gemm_sk(
    const void* __restrict__ Ap, const float* __restrict__ W,
    float* __restrict__ part, int M, int N, int K, int KS)
{
  __shared__ __align__(16) unsigned short As[64][40];  // [m][k]
  __shared__ __align__(16) unsigned short Bs[64][40];  // [n][k^swz]
  const int tid = threadIdx.x, lane = tid & 63, wave = tid >> 6;
  const int wm = wave >> 1, wn = wave & 1;
  const int n0 = blockIdx.x * 64, m0 = blockIdx.y * 64;
  const int kbase = blockIdx.z * KS;
  f32x4 acc[2][2] = {};
  for (int kq = 0; kq < KS; kq += 32){
    int kk = kbase + kq;
    { int m = tid >> 2, k4 = (tid & 3) * 8;
      if (AK == 0){
        const float* ap = (const float*)Ap + (size_t)(m0 + m) * K + kk + k4;
        #pragma unroll
        for (int i = 0; i < 8; ++i) As[m][k4 + i] = f2bf(ap[i]);
      } else {
        const unsigned short* ap = (const unsigned short*)Ap + (size_t)(m0 + m) * K + kk + k4;
        *(bf16x8*)&As[m][k4] = *(const bf16x8*)ap;
      }
    }
    { int kr = tid >> 3, n8 = (tid & 7) * 8;
      const float* wp = W + (size_t)(kk + kr) * N + n0 + n8;
      #pragma unroll
      for (int i = 0; i < 8; ++i){
        int n = n8 + i;
        Bs[n][kr ^ (((n >> 3) & 3) << 3)] = f2bf(wp[i]);
      }
    }
    __syncthreads();
    const int kb = (lane >> 4) * 8;
    bf16x8 a[2], bfr[2];
    #pragma unroll
    for (int i = 0; i < 2; ++i) a[i] = *(const bf16x8*)&As[wm*32 + i*16 + (lane & 15)][kb];
    #pragma unroll
    for (int j = 0; j < 2; ++j){
      int n = wn*32 + j*16 + (lane & 15);
      bfr[j] = *(const bf16x8*)&Bs[n][kb ^ (((n >> 3) & 3) << 3)];
    }
    #pragma unroll
    for (int i = 0; i < 2; ++i)
      #pragma unroll
      for (int j = 0; j < 2; ++j) acc[i][j] = mfma16(a[i], bfr[j], acc[i][j]);
    __syncthreads();
  }
  float* pz = part + (size_t)blockIdx.z * M * N;
  #pragma unroll
  for (int i = 0; i < 2; ++i)
    #pragma unroll
    for (int j = 0; j < 2; ++j){
      int col = n0 + wn*32 + j*16 + (lane & 15);
      #pragma unroll
      for (int r = 0; r < 4; ++r){
        int row = m0 + wm*32 + i*16 + (lane >> 4) * 4 + r;
        pz[(size_t)row * N + col] = acc[i][j][r];
      }
    }
}

// ---------------- split-K reduce: out = sum_z part[z] + bias (+resid) ----------------
template<int RES>
__global__ __launch_bounds__(256) void k_reduce(
    const float* __restrict__ part, const float* __restrict__ bias,
    const float* __restrict__ resid, float* __restrict__ out,
    int total, int N, int SK)
{
  int i = blockIdx.x * 256 + threadIdx.x;
  if (i >= total) return;
  float s = 0.f;
  for (int z = 0; z < SK; ++z) s += part[(size_t)z * total + i];
  s += bias[i % N];
  if (RES) s += resid[i];
  out[i] = s;
}

// ---------------- fused split-K reduce + residual + LayerNorm ----------------
__global__ __launch_bounds__(256) void k_reduce_ln(
    const float* __restrict__ part, const float* __restrict__ bias,
    const float* __restrict__ resid,
    const float* __restrict__ g, const float* __restrict__ bb,
    float* __restrict__ emb_out, unsigned short* __restrict__ ln_out, int SK)
{
  __shared__ float red[4];
  const int t = blockIdx.x, tid = threadIdx.x;
  const int i = t * 256 + tid;
  float s = 0.f;
  for (int z = 0; z < SK; ++z) s += part[(size_t)z * 262144 + i];
  s += bias[tid] + resid[i];
  emb_out[i] = s;
  float mean = block_sum(s, red, tid) * (1.f / 256.f);
  float d = s - mean;
  float var = block_sum(d * d, red, tid) * (1.f / 256.f);
  ln_out[i] = f2bf(d * rsqrtf(var + 1e-5f) * g[tid] + bb[tid]);
}

// ---------------- attention: one (b,h) per block ----------------
__global__ __launch_bounds__(64) void k_attn(const float* __restrict__ qkv,
                                             float* __restrict__ attno)
{
  __shared__ float qs[64][33], ksm[64][33], vsm[64][33];
  const int blk = blockIdx.x, lane = threadIdx.x;
  const int b = blk >> 3, h = blk & 7;
  for (int idx = lane; idx < 2048; idx += 64){
    int row = idx >> 5, d = idx & 31;
    const float* base = qkv + (size_t)(b * 64 + row) * 768 + h * 32 + d;
    qs[row][d] = base[0]; ksm[row][d] = base[256]; vsm[row][d] = base[512];
  }
  __syncthreads();
  float qr[32];
  #pragma unroll
  for (int d = 0; d < 32; ++d) qr[d] = qs[lane][d];
  float s[64]; float mx = -1e30f;
  for (int m = 0; m < 64; ++m){
    float dot = 0.f;
    #pragma unroll
    for (int d = 0; d < 32; ++d) dot += qr[d] * ksm[m][d];
    dot *= 0.17677669529663687f;  // 32^-0.5
    s[m] = dot; mx = fmaxf(mx, dot);
  }
  float sum = 0.f;
  for (int m = 0; m < 64; ++m){ s[m] = expf(s[m] - mx); sum += s[m]; }
  float inv = 1.f / sum;
  float o[32] = {};
  for (int m = 0; m < 64; ++m){
    float p = s[m] * inv;
    #pragma unroll
    for (int d = 0; d < 32; ++d) o[d] += p * vsm[m][d];
  }
  float* dst = attno + (size_t)(b * 64 + lane) * 256 + h * 32;
  #pragma unroll
  for (int d = 0; d < 32; ++d) dst[d] = o[d];
}

__global__ void k_fill(float* p, int n, float v){
  int i = blockIdx.x * 256 + threadIdx.x;
  if (i < n) p[i] = v;
}

// ---------------- launch ----------------
extern "C" void kernel_launch(void* const* d_in, const int* in_sizes, int n_in,
                              void* d_out, int out_size, void* d_ws, size_t ws_size,
                              hipStream_t stream)
{
  const float* img      = (const float*)d_in[0];
  const float* embed    = (const float*)d_in[1];
  const float* roi      = (const float*)d_in[2];
  const float* ln_adj_g = (const float*)d_in[3];
  const float* ln_adj_b = (const float*)d_in[4];
  const float* w_adj    = (const float*)d_in[5];
  const float* ln_off_g = (const float*)d_in[6];
  const float* ln_off_b = (const float*)d_in[7];
  const float* w_off    = (const float*)d_in[8];
  const float* off_bias = (const float*)d_in[9];
  const float* pg_ln_g  = (const float*)d_in[10];
  const float* pg_ln_b  = (const float*)d_in[11];
  const float* pg_w1    = (const float*)d_in[12];
  const float* pg_b1    = (const float*)d_in[13];
  const float* pg_w2    = (const float*)d_in[14];
  const float* pg_b2    = (const float*)d_in[15];
  const float* m_beta   = (const float*)d_in[16];
  const float* s_beta   = (const float*)d_in[17];
  const float* mix_w    = (const float*)d_in[18];
  const float* mix_b    = (const float*)d_in[19];
  const float* ln1_g    = (const float*)d_in[20];
  const float* ln1_b    = (const float*)d_in[21];
  const float* qkv_w    = (const float*)d_in[22];
  const float* qkv_b    = (const float*)d_in[23];
  const float* proj_w   = (const float*)d_in[24];
  const float* proj_b   = (const float*)d_in[25];
  const float* ln2_g    = (const float*)d_in[26];
  const float* ln2_b    = (const float*)d_in[27];
  const float* fc1_w    = (const float*)d_in[28];
  const float* fc1_b    = (const float*)d_in[29];
  const float* fc2_w    = (const float*)d_in[30];
  const float* fc2_b    = (const float*)d_in[31];

  char* ws = (char*)d_ws;
  float*          pts     = (float*)         (ws + 0);          //   294912
  float*          hbuf    = (float*)         (ws + 294912);     //   262144
  unsigned short* imgT    = (unsigned short*)(ws + 557056);     // 33554432
  unsigned short* sampled = (unsigned short*)(ws + 34111488);   // 18874368
  unsigned short* params3 = (unsigned short*)(ws + 52985856);   // 136970240 (1045*65536*2)
  unsigned short* out2    = (unsigned short*)(ws + 189956096);  // 18874368
  float*          embed1  = (float*)         (ws + 208830464);  //  1048576
  float*          embed2  = (float*)         (ws + 209879040);  //  1048576
  unsigned short* xln1    = (unsigned short*)(ws + 210927616);  //   524288
  unsigned short* xln2    = (unsigned short*)(ws + 211451904);  //   524288
  float*          qkvb    = (float*)         (ws + 211976192);  //  3145728
  float*          attno   = (float*)         (ws + 215121920);  //  1048576
  // aliased into the params3 region (dead after k_mixtoken):
  float*          part_mix  = (float*)(ws + 52985856);             // 16 MB (16 slabs)
  float*          part_smll = (float*)(ws + 52985856 + 16777216);  //  4 MB (4 slabs)
  unsigned short* h1        = (unsigned short*)(ws + 52985856 + 20971520); // 2 MB
  const size_t WS_NEEDED = 216170496;
  if (ws_size < WS_NEEDED){
    k_fill<<<(out_size + 255) / 256, 256, 0, stream>>>((float*)d_out, out_size, 12345.0f);
    return;
  }

  float* out = (float*)d_out;

  k_prep<<<1024, 256, 0, stream>>>(embed, roi, ln_adj_g, ln_adj_b, w_adj,
                                   ln_off_g, ln_off_b, w_off, off_bias,
                                   pg_ln_g, pg_ln_b, pg_w1, pg_b1, pts, hbuf);
  k_transpose<<<1024, 256, 0, stream>>>(img, imgT);
  k_sample<<<1024, 256, 0, stream>>>(imgT, pts, sampled);
  k_params<<<1045, 256, 0, stream>>>(hbuf, pg_w2, pg_b2, params3);
  k_mixtoken<<<1024, 256, 0, stream>>>(sampled, params3, m_beta, s_beta, out2);
  // embed1 = embed + out2 @ mix_w + mix_b   (split-K: 9216 = 16 x 576), fused LN1
  k_gemm_sk<1><<<dim3(4,16,16), 256, 0, stream>>>(out2, mix_w, part_mix, 1024, 256, 9216, 576);
  k_reduce_ln<<<1024, 256, 0, stream>>>(part_mix, mix_b, embed, ln1_g, ln1_b, embed1, xln1, 16);
  k_gemm<1,0,0,0><<<dim3(12,16), 256, 0, stream>>>(xln1, qkv_w, qkv_b, nullptr, qkvb, 1024, 768, 256);
  k_attn<<<128, 64, 0, stream>>>(qkvb, attno);
  // embed2 = embed1 + attno @ proj_w + proj_b (split-K: 256 = 4 x 64), fused LN2
  k_gemm_sk<0><<<dim3(4,16,4), 256, 0, stream>>>(attno, proj_w, part_smll, 1024, 256, 256, 64);
  k_reduce_ln<<<1024, 256, 0, stream>>>(part_smll, proj_b, embed1, ln2_g, ln2_b, embed2, xln2, 4);
  k_gemm<1,1,0,1><<<dim3(16,16), 256, 0, stream>>>(xln2, fc1_w, fc1_b, nullptr, h1, 1024, 1024, 256);
  // out = embed2 + h1 @ fc2_w + fc2_b   (split-K: 1024 = 4 x 256)
  k_gemm_sk<1><<<dim3(4,16,4), 256, 0, stream>>>(h1, fc2_w, part_smll, 1024, 256, 1024, 256);
  k_reduce<1><<<1024, 256, 0, stream>>>(part_smll, fc2_b, embed2, out, 262144, 256, 4);
}